// Round 1
// baseline (174.731 us; speedup 1.0000x reference)
//
#include <hip/hip_runtime.h>
#include <math.h>

#define HH 256
#define WW 256
static constexpr int HW = HH * WW;
static constexpr float MIN_D = 0.1f;
static constexpr float MAX_D = 10.0f;
static constexpr float C1c = 1e-4f;   // 0.01^2
static constexpr float C2c = 9e-4f;   // 0.03^2

__device__ inline unsigned shdu(unsigned v, int o) {
    return (unsigned)__shfl_down((int)v, o, 64);
}

// ---------------------------------------------------------------------------
// Stage 1: weighted z-buffer scatter. 4 points per thread via float4 loads.
// ---------------------------------------------------------------------------
__global__ void scatter_k(const float* __restrict__ pts, const float* __restrict__ dens,
                          float* __restrict__ zw, float* __restrict__ wm,
                          int nthreads, int N) {
    int t = blockIdx.x * blockDim.x + threadIdx.x;
    if (t >= nthreads) return;
    const float4* p4 = (const float4*)pts;
    float4 a = p4[3 * t];
    float4 b4 = p4[3 * t + 1];
    float4 c = p4[3 * t + 2];
    float xs[4] = {a.x, a.w, b4.z, c.y};
    float ys[4] = {a.y, b4.x, b4.w, c.z};
    float zs[4] = {a.z, b4.y, c.x, c.w};
    int base = 4 * t;
    int b = base / N;              // N % 4 == 0, so all 4 points share a batch
    float* zwb = zw + (size_t)b * HW;
    float* wmb = wm + (size_t)b * HW;
#pragma unroll
    for (int k = 0; k < 4; ++k) {
        float z = zs[k];
        if (!(z > MIN_D)) continue;          // valid requires z > MIN_DEPTH (strict)
        float u = (xs[k] / z + 0.5f) * (float)WW;
        float v = (ys[k] / z + 0.5f) * (float)HH;
        if (!(u >= 0.f && u < (float)WW && v >= 0.f && v < (float)HH)) continue;
        int ui = (int)floorf(u);
        int vi = (int)floorf(v);
        if (ui < 0) ui = 0; if (ui > WW - 1) ui = WW - 1;
        if (vi < 0) vi = 0; if (vi > HH - 1) vi = HH - 1;
        float d = dens[base + k];            // load only for valid points
        float w = 1.f / (1.f + expf(-d));    // sigmoid
        int idx = vi * WW + ui;
        atomicAdd(&zwb[idx], z * w);
        atomicAdd(&wmb[idx], w);
    }
}

// ---------------------------------------------------------------------------
// Stage 2: depth = zw/wm (where wm>0), per-batch min/max of valid pred & gt.
// mm layout: [0..3]=minP, [4..7]=minG, [8..11]=maxP, [12..15]=maxG (uint bits)
// ---------------------------------------------------------------------------
__global__ void finalize_k(const float* __restrict__ zw, const float* __restrict__ wm,
                           const float* __restrict__ gt, float* __restrict__ raw,
                           unsigned* __restrict__ mm) {
    int i = blockIdx.x * 256 + threadIdx.x;
    int b = blockIdx.x >> 8;
    float ws = wm[i];
    float d = ws > 0.f ? zw[i] / ws : 0.f;
    raw[i] = d;
    float g = gt[i];
    unsigned dmin = d > 0.f ? __float_as_uint(d) : 0xFFFFFFFFu;
    unsigned dmax = d > 0.f ? __float_as_uint(d) : 0u;
    unsigned gmin = g > 0.f ? __float_as_uint(g) : 0xFFFFFFFFu;
    unsigned gmax = g > 0.f ? __float_as_uint(g) : 0u;
    for (int o = 32; o; o >>= 1) {
        dmin = min(dmin, shdu(dmin, o));
        gmin = min(gmin, shdu(gmin, o));
        dmax = max(dmax, shdu(dmax, o));
        gmax = max(gmax, shdu(gmax, o));
    }
    __shared__ unsigned sm[4][4];
    int wid = threadIdx.x >> 6, lane = threadIdx.x & 63;
    if (lane == 0) { sm[0][wid] = dmin; sm[1][wid] = gmin; sm[2][wid] = dmax; sm[3][wid] = gmax; }
    __syncthreads();
    if (threadIdx.x == 0) {
        unsigned m0 = min(min(sm[0][0], sm[0][1]), min(sm[0][2], sm[0][3]));
        unsigned m1 = min(min(sm[1][0], sm[1][1]), min(sm[1][2], sm[1][3]));
        unsigned m2 = max(max(sm[2][0], sm[2][1]), max(sm[2][2], sm[2][3]));
        unsigned m3 = max(max(sm[3][0], sm[3][1]), max(sm[3][2], sm[3][3]));
        atomicMin(&mm[b], m0);
        atomicMin(&mm[4 + b], m1);
        atomicMax(&mm[8 + b], m2);
        atomicMax(&mm[12 + b], m3);
    }
}

// ---------------------------------------------------------------------------
// Stage 3: normalize pred (in place) and gt into imgg.
// ---------------------------------------------------------------------------
__global__ void normalize_k(float* __restrict__ imgp, const float* __restrict__ gt,
                            float* __restrict__ imgg, const unsigned* __restrict__ mm) {
    int i = blockIdx.x * 256 + threadIdx.x;
    int b = blockIdx.x >> 8;
    bool hasP = mm[8 + b] != 0u;
    float pmin = __uint_as_float(mm[b]);
    float pmax = __uint_as_float(mm[8 + b]);
    float pmin_m = hasP ? fmaxf(pmin, MIN_D) : 0.f;
    float pmax_m = hasP ? fminf(pmax, MAX_D) : MAX_D;
    float d = imgp[i];
    imgp[i] = (d - pmin_m) / (pmax_m - pmin_m + 1e-8f) * (d > 0.f ? 1.f : 0.f);
    bool hasG = mm[12 + b] != 0u;
    float gmin = __uint_as_float(mm[4 + b]);
    float gmax = __uint_as_float(mm[12 + b]);
    float gmin_m = hasG ? fmaxf(gmin, MIN_D) : 0.f;
    float gmax_m = hasG ? fminf(gmax, MAX_D) : MAX_D;
    float g = gt[i];
    imgg[i] = (g - gmin_m) / (gmax_m - gmin_m + 1e-8f) * (g > 0.f ? 1.f : 0.f);
}

// ---------------------------------------------------------------------------
// Stage 4: 11x11 zero-padded box SSIM + masked L1, block-reduced into accum.
// accum[0]=ssim_sum, accum[1]=mask_sum, accum[2]=l1_sum
// ---------------------------------------------------------------------------
__global__ void ssim_k(const float* __restrict__ proj, const float* __restrict__ gtn,
                       float* __restrict__ accum) {
    int px = blockIdx.x * 16 + threadIdx.x;
    int py = blockIdx.y * 16 + threadIdx.y;
    const float* P = proj + (size_t)blockIdx.z * HW;
    const float* T = gtn + (size_t)blockIdx.z * HW;
    float s1 = 0, s2 = 0, s11 = 0, s22 = 0, s12 = 0;
    int ylo = py - 5 < 0 ? 0 : py - 5;
    int yhi = py + 5 > HH - 1 ? HH - 1 : py + 5;
    int xlo = px - 5 < 0 ? 0 : px - 5;
    int xhi = px + 5 > WW - 1 ? WW - 1 : px + 5;
    for (int yy = ylo; yy <= yhi; ++yy) {
        const float* Pr = P + yy * WW;
        const float* Tr = T + yy * WW;
        for (int xx = xlo; xx <= xhi; ++xx) {
            float p = Pr[xx], t = Tr[xx];
            s1 += p; s2 += t;
            s11 += p * p; s22 += t * t; s12 += p * t;
        }
    }
    float mu1 = s1 / 121.f, mu2 = s2 / 121.f;
    float mu1sq = mu1 * mu1, mu2sq = mu2 * mu2, mu12 = mu1 * mu2;
    float sig1 = s11 / 121.f - mu1sq;
    float sig2 = s22 / 121.f - mu2sq;
    float sig12 = s12 / 121.f - mu12;
    float smap = (2.f * mu12 + C1c) * (2.f * sig12 + C2c) /
                 ((mu1sq + mu2sq + C1c) * (sig1 + sig2 + C2c));
    float pc = P[py * WW + px], tc = T[py * WW + px];
    float m = (pc > 0.f && tc > 0.f) ? 1.f : 0.f;
    float sv = smap * m;
    float lv = m * fabsf(pc - tc);
    int tid = threadIdx.y * 16 + threadIdx.x;
    for (int o = 32; o; o >>= 1) {
        sv += __shfl_down(sv, o, 64);
        m  += __shfl_down(m, o, 64);
        lv += __shfl_down(lv, o, 64);
    }
    __shared__ float sb[3][4];
    int wid = tid >> 6, lane = tid & 63;
    if (lane == 0) { sb[0][wid] = sv; sb[1][wid] = m; sb[2][wid] = lv; }
    __syncthreads();
    if (tid == 0) {
        atomicAdd(&accum[0], sb[0][0] + sb[0][1] + sb[0][2] + sb[0][3]);
        atomicAdd(&accum[1], sb[1][0] + sb[1][1] + sb[1][2] + sb[1][3]);
        atomicAdd(&accum[2], sb[2][0] + sb[2][1] + sb[2][2] + sb[2][3]);
    }
}

// ---------------------------------------------------------------------------
// Stage 5: scalar combine.
// ---------------------------------------------------------------------------
__global__ void final_k(const float* __restrict__ accum, float* __restrict__ out) {
    float msum = accum[1];
    float l1 = accum[2] / (msum + 1e-8f);
    float ssim = 1.f - accum[0] / (msum + 1e-8f);
    float total = fminf(0.8f * l1 + 0.2f * ssim, 1.0f);
    out[0] = (msum < 10.f) ? 0.f : total;
}

extern "C" void kernel_launch(void* const* d_in, const int* in_sizes, int n_in,
                              void* d_out, int out_size, void* d_ws, size_t ws_size,
                              hipStream_t stream) {
    const float* pts = (const float*)d_in[0];
    const float* dens = (const float*)d_in[1];
    const float* gt = (const float*)d_in[2];
    int B = in_sizes[2] / HW;      // 4
    int N = in_sizes[1] / B;       // 2,000,000

    float* ws = (float*)d_ws;
    float* zw   = ws;
    float* wm   = ws + (size_t)B * HW;
    float* imgp = ws + 2 * (size_t)B * HW;
    float* imgg = ws + 3 * (size_t)B * HW;
    unsigned* mm = (unsigned*)(ws + 4 * (size_t)B * HW);
    float* accum = (float*)(mm + 16);

    // zero the scatter accumulators; init min slots to 0xFFFFFFFF, max+accum to 0
    hipMemsetAsync(zw, 0, (size_t)2 * B * HW * sizeof(float), stream);
    hipMemsetAsync(mm, 0xFF, 8 * sizeof(unsigned), stream);
    hipMemsetAsync(mm + 8, 0, 8 * sizeof(unsigned) + 4 * sizeof(float), stream);

    int nthreads = (B * N) / 4;
    scatter_k<<<(nthreads + 255) / 256, 256, 0, stream>>>(pts, dens, zw, wm, nthreads, N);
    finalize_k<<<B * 256, 256, 0, stream>>>(zw, wm, gt, imgp, mm);
    normalize_k<<<B * 256, 256, 0, stream>>>(imgp, gt, imgg, mm);
    ssim_k<<<dim3(16, 16, B), dim3(16, 16), 0, stream>>>(imgp, imgg, accum);
    final_k<<<1, 1, 0, stream>>>(accum, (float*)d_out);
}